// Round 2
// baseline (994.049 us; speedup 1.0000x reference)
//
#include <hip/hip_runtime.h>

#define N_VOXELS 150000
#define NP 60000
#define NK 27
#define CIN 32
#define COUT 64
#define BN_EPS 1e-5f
#define NELEM (N_VOXELS * COUT)

#define RVOX 64                                  // voxels per range (block)
#define NR ((N_VOXELS + RVOX - 1) / RVOX)        // 2344 ranges
#define CAP 1024                                 // bucket capacity (avg 691, ~12 sigma)

// ws layout (in int32 units):
//   [0 .. NR)            range counters
//   [4096 .. 4096+128)   BN stats (float): sum[64], sumsq[64]
//   [8192 .. )           bucket lists, NR*CAP ints (~9.6 MB)
#define WS_CNT   0
#define WS_STATS 4096
#define WS_LIST  8192

// ---------------------------------------------------------------------------
// Kernel 1: build range buckets. entry = (k<<22) | (p<<6) | (vout & 63).
// p < 60000 fits in 16 bits; k < 27 in 5 bits; local voxel in 6 bits.
// ---------------------------------------------------------------------------
__global__ __launch_bounds__(256) void build_buckets(
    const int* __restrict__ out_idx, int* __restrict__ ws)
{
    const int k = blockIdx.y;
    const int p = blockIdx.x * 256 + threadIdx.x;
    if (p >= NP) return;
    const int v = out_idx[k * NP + p];
    const int r = v >> 6;
    const int slot = atomicAdd(&ws[WS_CNT + r], 1);
    if (slot < CAP)
        ws[WS_LIST + r * CAP + slot] = (k << 22) | (p << 6) | (v & 63);
}

// ---------------------------------------------------------------------------
// Kernel 2: gather conv per range. Bin entries by k in LDS, loop k with the
// weight column in VGPRs (lane = cout), accumulate into LDS via ds_add_f32.
// Epilogue: y = relu(acc + bias) -> coalesced store + fused BN-stats.
// ---------------------------------------------------------------------------
__global__ __launch_bounds__(256) void conv_gather(
    const float* __restrict__ features,
    const int* __restrict__ in_idx,
    const float* __restrict__ weight,
    const float* __restrict__ bias,
    const int* __restrict__ ws_i,
    float* __restrict__ out,
    float* __restrict__ stats)
{
    __shared__ float accum[RVOX * COUT];   // 16 KB
    __shared__ int   kbin[CAP];            // 4 KB
    __shared__ int   khist[NK];
    __shared__ int   koff[NK + 1];
    __shared__ int   kcur[NK];
    __shared__ float lsum[COUT];
    __shared__ float lsq[COUT];

    const int r    = blockIdx.x;
    const int tid  = threadIdx.x;
    const int lane = tid & 63;
    const int wid  = tid >> 6;

    int n = ws_i[WS_CNT + r];
    if (n > CAP) n = CAP;
    const int* list = ws_i + WS_LIST + (size_t)r * CAP;

    for (int i = tid; i < RVOX * COUT; i += 256) accum[i] = 0.f;
    if (tid < NK) khist[tid] = 0;
    if (tid < COUT) { lsum[tid] = 0.f; lsq[tid] = 0.f; }
    __syncthreads();

    // histogram by k
    for (int i = tid; i < n; i += 256) atomicAdd(&khist[list[i] >> 22], 1);
    __syncthreads();
    if (tid == 0) {
        int acc = 0;
        for (int k = 0; k < NK; ++k) { koff[k] = acc; kcur[k] = acc; acc += khist[k]; }
        koff[NK] = acc;
    }
    __syncthreads();
    // place into k-sorted LDS bins
    for (int i = tid; i < n; i += 256) {
        const int pk = list[i];
        const int slot = atomicAdd(&kcur[pk >> 22], 1);
        kbin[slot] = pk;
    }
    __syncthreads();

    // k-loop: weight column in VGPRs, waves share each bin with stride 4
    for (int k = 0; k < NK; ++k) {
        const int b0 = koff[k], b1 = koff[k + 1];
        if (b0 == b1) continue;
        float w[CIN];
        const float* wk = weight + k * (CIN * COUT) + lane;
#pragma unroll
        for (int c = 0; c < CIN; ++c) w[c] = wk[c * COUT];

        for (int i = b0 + wid; i < b1; i += 4) {
            const int pk  = kbin[i];                   // wave-uniform broadcast
            const int p   = (pk >> 6) & 0xFFFF;
            const int lv  = pk & 63;
            const int vin = in_idx[k * NP + p];        // wave-uniform
            const float4* f4 = reinterpret_cast<const float4*>(features + (size_t)vin * CIN);
            float s0 = 0.f, s1 = 0.f, s2 = 0.f, s3 = 0.f;
#pragma unroll
            for (int q = 0; q < CIN / 4; ++q) {
                const float4 v = f4[q];                // broadcast load
                s0 = fmaf(v.x, w[4 * q + 0], s0);
                s1 = fmaf(v.y, w[4 * q + 1], s1);
                s2 = fmaf(v.z, w[4 * q + 2], s2);
                s3 = fmaf(v.w, w[4 * q + 3], s3);
            }
            atomicAdd(&accum[lv * COUT + lane], (s0 + s1) + (s2 + s3));  // ds_add_f32
        }
    }
    __syncthreads();

    // epilogue: y = relu(acc + bias), coalesced store, fused BN stats
    const int v0 = r * RVOX;
    const int nv = (N_VOXELS - v0 < RVOX) ? (N_VOXELS - v0) : RVOX;
    const float b = bias[lane];                        // channel == lane (stride 256 % 64 == 0)
    for (int i = tid; i < nv * COUT; i += 256) {
        float y = accum[i] + b;
        y = fmaxf(y, 0.f);
        out[(size_t)v0 * COUT + i] = y;
        atomicAdd(&lsum[lane], y);                     // 2-way bank, free
        atomicAdd(&lsq[lane], y * y);
    }
    __syncthreads();
    if (tid < COUT) atomicAdd(&stats[tid], lsum[tid]);
    else if (tid < 2 * COUT) atomicAdd(&stats[tid], lsq[tid - COUT]);
}

// ---------------------------------------------------------------------------
// Kernel 3: in-place BN apply on y (already ReLU'd), float4-vectorized.
// ---------------------------------------------------------------------------
__global__ __launch_bounds__(256) void bn_apply(
    float* __restrict__ buf,
    const float* __restrict__ stats,
    const float* __restrict__ gamma,
    const float* __restrict__ beta)
{
    const float inv_n = 1.f / (float)N_VOXELS;
    const int cg = (threadIdx.x & 15) * 4;             // 4-channel group, stable per thread
    float sc[4], sh[4];
#pragma unroll
    for (int j = 0; j < 4; ++j) {
        const int c = cg + j;
        const float mean = stats[c] * inv_n;
        const float var  = stats[COUT + c] * inv_n - mean * mean;
        sc[j] = gamma[c] * rsqrtf(var + BN_EPS);
        sh[j] = beta[c] - mean * sc[j];
    }
    const int tid    = blockIdx.x * 256 + threadIdx.x;
    const int stride = gridDim.x * 256;                // multiple of 16 -> channel group stable
    float4* buf4 = reinterpret_cast<float4*>(buf);
    for (int i = tid; i < NELEM / 4; i += stride) {
        float4 y = buf4[i];
        y.x = fmaf(y.x, sc[0], sh[0]);
        y.y = fmaf(y.y, sc[1], sh[1]);
        y.z = fmaf(y.z, sc[2], sh[2]);
        y.w = fmaf(y.w, sc[3], sh[3]);
        buf4[i] = y;
    }
}

extern "C" void kernel_launch(void* const* d_in, const int* in_sizes, int n_in,
                              void* d_out, int out_size, void* d_ws, size_t ws_size,
                              hipStream_t stream) {
    const float* features = (const float*)d_in[0];
    const int*   in_idx   = (const int*)d_in[1];
    const int*   out_idx  = (const int*)d_in[2];
    const float* weight   = (const float*)d_in[3];
    const float* bias     = (const float*)d_in[4];
    const float* gamma    = (const float*)d_in[5];
    const float* beta     = (const float*)d_in[6];
    float* out   = (float*)d_out;
    int*   ws    = (int*)d_ws;
    float* stats = (float*)d_ws + WS_STATS;

    // zero counters + stats (first 32 KB of ws); bucket payload needs no init
    hipMemsetAsync(d_ws, 0, (size_t)WS_LIST * sizeof(int), stream);

    dim3 bgrid((NP + 255) / 256, NK);
    build_buckets<<<bgrid, 256, 0, stream>>>(out_idx, ws);

    conv_gather<<<NR, 256, 0, stream>>>(features, in_idx, weight, bias, ws, out, stats);

    bn_apply<<<2048, 256, 0, stream>>>(out, stats, gamma, beta);
}